// Round 2
// baseline (1224.173 us; speedup 1.0000x reference)
//
#include <hip/hip_runtime.h>

// Problem constants (from reference): WIDTH=64 -> S=4096, E=128, B=8,
// edges per batch = 32 paths * 16 edges = 512.
#define WIDTH 64
#define S 4096
#define E 128
#define BATCH 8
#define EDGES_PER_B 512
#define TOTAL_EDGES (BATCH * EDGES_PER_B)

// Single streaming pass over the ENTIRE d_out:
//   [0, B*S*E)            attn region  -> broadcast bp
//   [B*S*E, B*S*E+2*B*S*S) two A copies -> zeros
// 272,629,760 floats = 68,157,440 float4 stores, perfectly coalesced.
__global__ void write_out_kernel(float* __restrict__ out,
                                 const float* __restrict__ bp) {
    __shared__ float sbp[E];
    if (threadIdx.x < E) sbp[threadIdx.x] = bp[threadIdx.x];
    __syncthreads();
    const int ATTN4 = BATCH * S * E / 4;                       // 1,048,576
    const long long N4 = (long long)BATCH * S * E / 4
                       + (long long)2 * BATCH * S * S / 4;     // 68,157,440
    float4* o4 = reinterpret_cast<float4*>(out);
    const long long stride = (long long)gridDim.x * blockDim.x;
    const float4 zero = make_float4(0.f, 0.f, 0.f, 0.f);
    for (long long i = (long long)blockIdx.x * blockDim.x + threadIdx.x;
         i < N4; i += stride) {
        float4 v;
        if (i < ATTN4) {
            int e0 = (((int)i) * 4) & (E - 1);
            v = make_float4(sbp[e0], sbp[e0 + 1], sbp[e0 + 2], sbp[e0 + 3]);
        } else {
            v = zero;
        }
        o4[i] = v;
    }
}

// Mark first occurrence of each (src,dst) pair per batch.
// A.at[...].set(1.0) semantics: duplicate edges count ONCE in hidden.
__global__ void dedupe_kernel(const int* __restrict__ edges,
                              int* __restrict__ flags) {
    const int b = blockIdx.x;
    __shared__ int keys[EDGES_PER_B];
    const int4* eb = reinterpret_cast<const int4*>(edges) + b * EDGES_PER_B;
    for (int i = threadIdx.x; i < EDGES_PER_B; i += blockDim.x) {
        int4 e = eb[i];                 // [x0, y0, x1, y1]
        int src = e.y * WIDTH + e.x;    // node = y*WIDTH + x
        int dst = e.w * WIDTH + e.z;
        keys[i] = src * S + dst;        // fits in 24 bits
    }
    __syncthreads();
    for (int i = threadIdx.x; i < EDGES_PER_B; i += blockDim.x) {
        int k = keys[i];
        int uniq = 1;
        for (int j = 0; j < i; ++j) {
            if (keys[j] == k) { uniq = 0; break; }
        }
        flags[b * EDGES_PER_B + i] = uniq;
    }
}

// One block (128 threads) per edge:
//  - set A[b,src,dst] = 1 in both output copies
//  - if first occurrence: attn[b,src,:] += (values[b,dst,:]@Wv + bv) @ Wp
__global__ void scatter_kernel(const int* __restrict__ edges,
                               const int* __restrict__ flags,
                               const float* __restrict__ values,
                               const float* __restrict__ Wv,
                               const float* __restrict__ bv,
                               const float* __restrict__ Wp,
                               float* __restrict__ attn,
                               float* __restrict__ A1,
                               float* __restrict__ A2) {
    const int g = blockIdx.x;           // edge index, 0..4095
    const int b = g >> 9;               // / EDGES_PER_B
    int4 e = reinterpret_cast<const int4*>(edges)[g];
    const int src = e.y * WIDTH + e.x;
    const int dst = e.w * WIDTH + e.z;
    const int aidx = (b * S + src) * S + dst;   // < 2^27, fits int
    if (threadIdx.x == 0) A1[aidx] = 1.0f;
    if (threadIdx.x == 1) A2[aidx] = 1.0f;
    if (!flags[g]) return;              // block-uniform, safe

    __shared__ float sv[E];
    __shared__ float hv[E];
    const int t = threadIdx.x;
    sv[t] = values[(b * S + dst) * E + t];
    __syncthreads();
    float acc = bv[t];
#pragma unroll 8
    for (int k = 0; k < E; ++k) acc += sv[k] * Wv[k * E + t];
    hv[t] = acc;
    __syncthreads();
    float p = 0.0f;
#pragma unroll 8
    for (int k = 0; k < E; ++k) p += hv[k] * Wp[k * E + t];
    atomicAdd(&attn[(b * S + src) * E + t], p);
}

extern "C" void kernel_launch(void* const* d_in, const int* in_sizes, int n_in,
                              void* d_out, int out_size, void* d_ws,
                              size_t ws_size, hipStream_t stream) {
    // setup_inputs order:
    // 0 queries, 1 keys, 2 values, 3 oracle_edges, 4 Wq, 5 bq, 6 Wk, 7 bk,
    // 8 Wv, 9 bv, 10 Wp, 11 bp
    const float* values = (const float*)d_in[2];
    const int*   edges  = (const int*)d_in[3];
    const float* Wv     = (const float*)d_in[8];
    const float* bv     = (const float*)d_in[9];
    const float* Wp     = (const float*)d_in[10];
    const float* bp     = (const float*)d_in[11];

    float* out  = (float*)d_out;
    float* attn = out;                                  // [B,S,E]
    float* A1   = out + (size_t)BATCH * S * E;          // [B,S,S]
    float* A2   = A1 + (size_t)BATCH * S * S;           // [B,S,S] (copy)

    int* flags = (int*)d_ws;                            // 4096 ints

    // One streaming pass writes all 1.09 GB of d_out (bp-broadcast + zeros).
    // 4096 blocks x 256 threads: 64 float4 stores per thread, grid-stride.
    write_out_kernel<<<4096, 256, 0, stream>>>(out, bp);
    dedupe_kernel<<<BATCH, 256, 0, stream>>>(edges, flags);
    scatter_kernel<<<TOTAL_EDGES, 128, 0, stream>>>(edges, flags, values, Wv,
                                                    bv, Wp, attn, A1, A2);
}

// Round 4
// 1144.009 us; speedup vs baseline: 1.0701x; 1.0701x over previous
//
#include <hip/hip_runtime.h>

// Problem constants (from reference): WIDTH=64 -> S=4096, E=128, B=8,
// edges per batch = 32 paths * 16 edges = 512.
#define WIDTH 64
#define S 4096
#define E 128
#define BATCH 8
#define EDGES_PER_B 512
#define TOTAL_EDGES (BATCH * EDGES_PER_B)

typedef float vfloat4 __attribute__((ext_vector_type(4)));

// Broadcast bp across the attn_repr region: attn[b,s,e] = bp[e].
// Exactly one float4 store per thread: 4096 blocks x 256 threads
// = 1,048,576 stores = 16 MB. No loop, no branch in the hot path.
__global__ void init_attn_kernel(float* __restrict__ attn,
                                 const float* __restrict__ bp) {
    const int i = blockIdx.x * blockDim.x + threadIdx.x; // < 1,048,576
    const int e0 = (i * 4) & (E - 1);
    // bp is 512 B -> L2/L1 resident after first wave; direct loads are fine.
    vfloat4 v = {bp[e0], bp[e0 + 1], bp[e0 + 2], bp[e0 + 3]};
    __builtin_nontemporal_store(v, reinterpret_cast<vfloat4*>(attn) + i);
}

// Mark first occurrence of each (src,dst) pair per batch.
// A.at[...].set(1.0) semantics: duplicate edges count ONCE in hidden.
__global__ void dedupe_kernel(const int* __restrict__ edges,
                              int* __restrict__ flags) {
    const int b = blockIdx.x;
    __shared__ int keys[EDGES_PER_B];
    const int4* eb = reinterpret_cast<const int4*>(edges) + b * EDGES_PER_B;
    for (int i = threadIdx.x; i < EDGES_PER_B; i += blockDim.x) {
        int4 e = eb[i];                 // [x0, y0, x1, y1]
        int src = e.y * WIDTH + e.x;    // node = y*WIDTH + x
        int dst = e.w * WIDTH + e.z;
        keys[i] = src * S + dst;        // fits in 24 bits
    }
    __syncthreads();
    for (int i = threadIdx.x; i < EDGES_PER_B; i += blockDim.x) {
        int k = keys[i];
        int uniq = 1;
        for (int j = 0; j < i; ++j) {
            if (keys[j] == k) { uniq = 0; break; }
        }
        flags[b * EDGES_PER_B + i] = uniq;
    }
}

// One block (128 threads) per edge:
//  - set A[b,src,dst] = 1 in both output copies
//  - if first occurrence: attn[b,src,:] += (values[b,dst,:]@Wv + bv) @ Wp
__global__ void scatter_kernel(const int* __restrict__ edges,
                               const int* __restrict__ flags,
                               const float* __restrict__ values,
                               const float* __restrict__ Wv,
                               const float* __restrict__ bv,
                               const float* __restrict__ Wp,
                               float* __restrict__ attn,
                               float* __restrict__ A1,
                               float* __restrict__ A2) {
    const int g = blockIdx.x;           // edge index, 0..4095
    const int b = g >> 9;               // / EDGES_PER_B
    int4 e = reinterpret_cast<const int4*>(edges)[g];
    const int src = e.y * WIDTH + e.x;
    const int dst = e.w * WIDTH + e.z;
    const int aidx = (b * S + src) * S + dst;   // < 2^27, fits int
    if (threadIdx.x == 0) A1[aidx] = 1.0f;
    if (threadIdx.x == 1) A2[aidx] = 1.0f;
    if (!flags[g]) return;              // block-uniform, safe

    __shared__ float sv[E];
    __shared__ float hv[E];
    const int t = threadIdx.x;
    sv[t] = values[(b * S + dst) * E + t];
    __syncthreads();
    float acc = bv[t];
#pragma unroll 8
    for (int k = 0; k < E; ++k) acc += sv[k] * Wv[k * E + t];
    hv[t] = acc;
    __syncthreads();
    float p = 0.0f;
#pragma unroll 8
    for (int k = 0; k < E; ++k) p += hv[k] * Wp[k * E + t];
    atomicAdd(&attn[(b * S + src) * E + t], p);
}

extern "C" void kernel_launch(void* const* d_in, const int* in_sizes, int n_in,
                              void* d_out, int out_size, void* d_ws,
                              size_t ws_size, hipStream_t stream) {
    // setup_inputs order:
    // 0 queries, 1 keys, 2 values, 3 oracle_edges, 4 Wq, 5 bq, 6 Wk, 7 bk,
    // 8 Wv, 9 bv, 10 Wp, 11 bp
    const float* values = (const float*)d_in[2];
    const int*   edges  = (const int*)d_in[3];
    const float* Wv     = (const float*)d_in[8];
    const float* bv     = (const float*)d_in[9];
    const float* Wp     = (const float*)d_in[10];
    const float* bp     = (const float*)d_in[11];

    float* out  = (float*)d_out;
    float* attn = out;                                  // [B,S,E]
    float* A1   = out + (size_t)BATCH * S * E;          // [B,S,S]
    float* A2   = A1 + (size_t)BATCH * S * S;           // [B,S,S] (copy)

    int* flags = (int*)d_ws;                            // 4096 ints

    // Zero both A copies (1.07 GB). The runtime fill engine runs at
    // ~6.25 TB/s (78% peak) — par with the best achievable write BW.
    (void)hipMemsetAsync(A1, 0, (size_t)2 * BATCH * S * S * sizeof(float),
                         stream);

    // bp broadcast over attn region (16 MB), one float4 store/thread.
    init_attn_kernel<<<4096, 256, 0, stream>>>(attn, bp);

    dedupe_kernel<<<BATCH, 256, 0, stream>>>(edges, flags);
    scatter_kernel<<<TOTAL_EDGES, 128, 0, stream>>>(edges, flags, values, Wv,
                                                    bv, Wp, attn, A1, A2);
}